// Round 1
// baseline (409.593 us; speedup 1.0000x reference)
//
#include <hip/hip_runtime.h>

// Problem constants (from setup_inputs): feat [B,N,D] fp32, assoc [B,M,N] fp32.
constexpr int Bn = 4;
constexpr int Mm = 4096;
constexpr int Nn = 4096;
constexpr int Dd = 64;
#define EPS_VAL 1e-6f

typedef __attribute__((ext_vector_type(8))) short short8_t;   // 8 x bf16 (4 VGPRs) — MFMA A/B frag
typedef __attribute__((ext_vector_type(4))) float floatx4;    // MFMA C/D frag

__device__ __forceinline__ unsigned short f32_to_bf16_rne(float x) {
    unsigned u = __float_as_uint(x);
    unsigned r = u + 0x7FFFu + ((u >> 16) & 1u);   // round-to-nearest-even
    return (unsigned short)(r >> 16);
}

// ---------------------------------------------------------------------------
// Kernel 1: feat [B,N,D] fp32  ->  Ft [B,D,N] bf16 (in d_ws).
// 64(n) x 64(d) tiles via LDS; one block per tile. 256 blocks total.
// (unchanged — measured negligible vs agg)
// ---------------------------------------------------------------------------
__global__ __launch_bounds__(256) void transpose_feat_kernel(
    const float* __restrict__ feat, unsigned short* __restrict__ ft)
{
    __shared__ unsigned short tile[64][66];   // +2 pad: column reads land ~conflict-free
    const int b  = blockIdx.x >> 6;           // Nn/64 = 64 tiles per batch
    const int n0 = (blockIdx.x & 63) * 64;
    const int t  = threadIdx.x;
    const int row = t >> 2;                   // 0..63
    const int seg = t & 3;                    // 0..3 (16 elements each)

    const float* src = feat + ((size_t)(b * Nn + n0 + row)) * Dd + seg * 16;
    #pragma unroll
    for (int v = 0; v < 4; ++v) {
        float4 f = ((const float4*)src)[v];
        tile[row][seg * 16 + v * 4 + 0] = f32_to_bf16_rne(f.x);
        tile[row][seg * 16 + v * 4 + 1] = f32_to_bf16_rne(f.y);
        tile[row][seg * 16 + v * 4 + 2] = f32_to_bf16_rne(f.z);
        tile[row][seg * 16 + v * 4 + 3] = f32_to_bf16_rne(f.w);
    }
    __syncthreads();

    const int d    = row;       // 0..63
    const int nseg = seg;       // 0..3
    short8_t v0, v1;
    #pragma unroll
    for (int i = 0; i < 8; ++i) v0[i] = (short)tile[nseg * 16 + i][d];
    #pragma unroll
    for (int i = 0; i < 8; ++i) v1[i] = (short)tile[nseg * 16 + 8 + i][d];

    unsigned short* dst = ft + ((size_t)(b * Dd + d)) * Nn + n0 + nseg * 16;
    *(short8_t*)(dst)     = v0;
    *(short8_t*)(dst + 8) = v1;
}

// ---------------------------------------------------------------------------
// Kernel 2: fused normalize + GEMM, v2 — occupancy fix.
// Old: 256 blocks (=CU count), __launch_bounds__(256,1) -> 1 wave/SIMD,
//      latency-bound at ~28% of HBM BW.
// New: grid = B * (M/16) = 1024 blocks x 4 waves. Each block owns ONE
//      16-row x 64-col output tile; the 4 waves split the N-reduction into
//      quarters (1024 k's each, K=64 per iteration). Partial accs + row-sum
//      partials are combined via a 13 KB LDS buffer; wave 0 does the epilogue.
// __launch_bounds__(256,4): VGPR<=128 -> 4 blocks/CU = 16 waves/CU = 4/SIMD.
// ---------------------------------------------------------------------------
__global__ __launch_bounds__(256, 4) void agg_kernel(
    const float* __restrict__ assoc, const unsigned short* __restrict__ ft,
    float* __restrict__ out)
{
    const int b  = blockIdx.x >> 8;          // Mm/16 = 256 m-tiles per batch
    const int mt = blockIdx.x & 255;
    const int w  = threadIdx.x >> 6;         // wave 0..3 = which N-quarter
    const int l  = threadIdx.x & 63;
    const int q  = l >> 4;                   // quad 0..3
    const int mi = l & 15;
    const int m0 = mt * 16;

    const int kbase = w * (Nn / 4) + q * 8;  // this wave's k-quarter, this quad's slab

    // A-frag source: lane holds A[m = mi][k = kbase + j], contiguous fp32.
    const float* aptr = assoc + ((size_t)b * Mm + (size_t)(m0 + mi)) * Nn + kbase;
    // B-frag source: lane holds B[k][n = d], contiguous in Ft[d][k]; d = mi + 16*db.
    const unsigned short* fptr = ft + (size_t)b * Dd * Nn + (size_t)mi * Nn + kbase;

    floatx4 acc0 = {0.f, 0.f, 0.f, 0.f};
    floatx4 acc1 = acc0, acc2 = acc0, acc3 = acc0;
    float s0 = 0.f, s1 = 0.f;                // row-sum partials (break the dep chain)

    // 16 iterations of K=64 (two 16x16x32 MFMA k-steps per iteration).
    #pragma unroll 1
    for (int k0 = 0; k0 < Nn / 4; k0 += 64) {
        float4 a0 = *(const float4*)(aptr + k0);
        float4 a1 = *(const float4*)(aptr + k0 + 4);
        float4 a2 = *(const float4*)(aptr + k0 + 32);
        float4 a3 = *(const float4*)(aptr + k0 + 36);

        const unsigned short* fp = fptr + k0;
        short8_t b00 = *(const short8_t*)(fp);
        short8_t b01 = *(const short8_t*)(fp + 16 * Nn);
        short8_t b02 = *(const short8_t*)(fp + 32 * Nn);
        short8_t b03 = *(const short8_t*)(fp + 48 * Nn);
        short8_t b10 = *(const short8_t*)(fp + 32);
        short8_t b11 = *(const short8_t*)(fp + 32 + 16 * Nn);
        short8_t b12 = *(const short8_t*)(fp + 32 + 32 * Nn);
        short8_t b13 = *(const short8_t*)(fp + 32 + 48 * Nn);

        short8_t af0, af1;
        {
            float av[8] = {a0.x, a0.y, a0.z, a0.w, a1.x, a1.y, a1.z, a1.w};
            #pragma unroll
            for (int j = 0; j < 8; ++j) {
                unsigned short h = f32_to_bf16_rne(av[j] + EPS_VAL);
                af0[j] = (short)h;
                float hv = __uint_as_float(((unsigned)h) << 16);
                if (j & 1) s1 += hv; else s0 += hv;
            }
        }
        {
            float av[8] = {a2.x, a2.y, a2.z, a2.w, a3.x, a3.y, a3.z, a3.w};
            #pragma unroll
            for (int j = 0; j < 8; ++j) {
                unsigned short h = f32_to_bf16_rne(av[j] + EPS_VAL);
                af1[j] = (short)h;
                float hv = __uint_as_float(((unsigned)h) << 16);
                if (j & 1) s1 += hv; else s0 += hv;
            }
        }

        acc0 = __builtin_amdgcn_mfma_f32_16x16x32_bf16(af0, b00, acc0, 0, 0, 0);
        acc1 = __builtin_amdgcn_mfma_f32_16x16x32_bf16(af0, b01, acc1, 0, 0, 0);
        acc2 = __builtin_amdgcn_mfma_f32_16x16x32_bf16(af0, b02, acc2, 0, 0, 0);
        acc3 = __builtin_amdgcn_mfma_f32_16x16x32_bf16(af0, b03, acc3, 0, 0, 0);
        acc0 = __builtin_amdgcn_mfma_f32_16x16x32_bf16(af1, b10, acc0, 0, 0, 0);
        acc1 = __builtin_amdgcn_mfma_f32_16x16x32_bf16(af1, b11, acc1, 0, 0, 0);
        acc2 = __builtin_amdgcn_mfma_f32_16x16x32_bf16(af1, b12, acc2, 0, 0, 0);
        acc3 = __builtin_amdgcn_mfma_f32_16x16x32_bf16(af1, b13, acc3, 0, 0, 0);
    }

    // Fold the quad partials within this wave: lane's s covers row mi, its k-subsets.
    // XOR over bits 4,5 sums all 4 quads -> every lane holds this wave's partial S(row mi).
    float s = s0 + s1;
    s += __shfl_xor(s, 16);
    s += __shfl_xor(s, 32);

    // Cross-wave reduction of the 4 N-quarter partials via LDS.
    // Stride 17 floats: (l*17 + i) % 32 is a permutation across 32 lanes -> conflict-free.
    __shared__ float redacc[3][64][17];
    if (w != 0) {
        float* p = redacc[w - 1][l];
        #pragma unroll
        for (int i = 0; i < 4; ++i) {
            p[i]      = acc0[i];
            p[4 + i]  = acc1[i];
            p[8 + i]  = acc2[i];
            p[12 + i] = acc3[i];
        }
        p[16] = s;
    }
    __syncthreads();

    if (w == 0) {
        #pragma unroll
        for (int ww = 0; ww < 3; ++ww) {
            const float* p = redacc[ww][l];
            #pragma unroll
            for (int i = 0; i < 4; ++i) {
                acc0[i] += p[i];
                acc1[i] += p[4 + i];
                acc2[i] += p[8 + i];
                acc3[i] += p[12 + i];
            }
            s += p[16];
        }

        // C/D layout: col = l&15 (d), row = q*4 + reg (m). Need S for rows q*4+r.
        #pragma unroll
        for (int r = 0; r < 4; ++r) {
            float Sr  = __shfl(s, q * 4 + r);    // lane (q*4+r) holds S for row mi==q*4+r
            float inv = 1.0f / Sr;
            size_t base = ((size_t)b * Mm + (size_t)(m0 + q * 4 + r)) * Dd + mi;
            out[base +  0] = acc0[r] * inv;
            out[base + 16] = acc1[r] * inv;
            out[base + 32] = acc2[r] * inv;
            out[base + 48] = acc3[r] * inv;
        }
    }
}

extern "C" void kernel_launch(void* const* d_in, const int* in_sizes, int n_in,
                              void* d_out, int out_size, void* d_ws, size_t ws_size,
                              hipStream_t stream) {
    const float* feat  = (const float*)d_in[0];   // [B,N,D] fp32
    const float* assoc = (const float*)d_in[1];   // [B,M,N] fp32
    float* out = (float*)d_out;                   // [B,M,D] fp32
    unsigned short* ft = (unsigned short*)d_ws;   // [B,D,N] bf16 scratch (2 MB)

    hipLaunchKernelGGL(transpose_feat_kernel, dim3(Bn * (Nn / 64)), dim3(256), 0, stream,
                       feat, ft);
    hipLaunchKernelGGL(agg_kernel, dim3(Bn * (Mm / 16)), dim3(256), 0, stream,
                       assoc, ft, out);
}

// Round 2
// 403.834 us; speedup vs baseline: 1.0143x; 1.0143x over previous
//
#include <hip/hip_runtime.h>

// Problem constants (from setup_inputs): feat [B,N,D] fp32, assoc [B,M,N] fp32.
constexpr int Bn = 4;
constexpr int Mm = 4096;
constexpr int Nn = 4096;
constexpr int Dd = 64;
#define EPS_VAL 1e-6f

typedef __attribute__((ext_vector_type(8))) short short8_t;   // 8 x bf16 (4 VGPRs) — MFMA A/B frag
typedef __attribute__((ext_vector_type(4))) float floatx4;    // MFMA C/D frag

__device__ __forceinline__ unsigned short f32_to_bf16_rne(float x) {
    unsigned u = __float_as_uint(x);
    unsigned r = u + 0x7FFFu + ((u >> 16) & 1u);   // round-to-nearest-even
    return (unsigned short)(r >> 16);
}

// ---------------------------------------------------------------------------
// Kernel 1: feat [B,N,D] fp32  ->  Ft [B,D,N] bf16 (in d_ws).
// 64(n) x 64(d) tiles via LDS; one block per tile. 256 blocks total.
// (unchanged — measured negligible vs agg)
// ---------------------------------------------------------------------------
__global__ __launch_bounds__(256) void transpose_feat_kernel(
    const float* __restrict__ feat, unsigned short* __restrict__ ft)
{
    __shared__ unsigned short tile[64][66];   // +2 pad: column reads land ~conflict-free
    const int b  = blockIdx.x >> 6;           // Nn/64 = 64 tiles per batch
    const int n0 = (blockIdx.x & 63) * 64;
    const int t  = threadIdx.x;
    const int row = t >> 2;                   // 0..63
    const int seg = t & 3;                    // 0..3 (16 elements each)

    const float* src = feat + ((size_t)(b * Nn + n0 + row)) * Dd + seg * 16;
    #pragma unroll
    for (int v = 0; v < 4; ++v) {
        float4 f = ((const float4*)src)[v];
        tile[row][seg * 16 + v * 4 + 0] = f32_to_bf16_rne(f.x);
        tile[row][seg * 16 + v * 4 + 1] = f32_to_bf16_rne(f.y);
        tile[row][seg * 16 + v * 4 + 2] = f32_to_bf16_rne(f.z);
        tile[row][seg * 16 + v * 4 + 3] = f32_to_bf16_rne(f.w);
    }
    __syncthreads();

    const int d    = row;       // 0..63
    const int nseg = seg;       // 0..3
    short8_t v0, v1;
    #pragma unroll
    for (int i = 0; i < 8; ++i) v0[i] = (short)tile[nseg * 16 + i][d];
    #pragma unroll
    for (int i = 0; i < 8; ++i) v1[i] = (short)tile[nseg * 16 + 8 + i][d];

    unsigned short* dst = ft + ((size_t)(b * Dd + d)) * Nn + n0 + nseg * 16;
    *(short8_t*)(dst)     = v0;
    *(short8_t*)(dst + 8) = v1;
}

// ---------------------------------------------------------------------------
// Kernel 2: fused normalize + GEMM, v3.
// Post-mortem of v2 (regressed): unroll-1 killed load pipelining, VGPR cap 128
// risked spills, 16-iter K-loops amortized badly. v3 keeps v1's PROVEN inner
// loop (unroll 4, K=32/iter, same frag pattern) and only doubles TLP:
//   grid = B * (M/32) = 512 blocks x 4 waves.
//   Waves (rg, nh): rg = row-group (16 rows each), nh = N-half (2048 k's).
//   2 blocks/CU (launch_bounds(256,2), VGPR<=256) -> 8 waves/CU = 2/SIMD.
// Pairwise epilogue reduce via 8.7 KB LDS (stride-17 rows, conflict-free).
// ---------------------------------------------------------------------------
__global__ __launch_bounds__(256, 2) void agg_kernel(
    const float* __restrict__ assoc, const unsigned short* __restrict__ ft,
    float* __restrict__ out)
{
    const int b  = blockIdx.x >> 7;          // Mm/32 = 128 m-tiles per batch
    const int mt = blockIdx.x & 127;
    const int w  = threadIdx.x >> 6;         // wave 0..3
    const int rg = w >> 1;                   // row-group 0/1 (rows m0..m0+15)
    const int nh = w & 1;                    // N-half 0/1
    const int l  = threadIdx.x & 63;
    const int q  = l >> 4;                   // quad 0..3
    const int mi = l & 15;
    const int m0 = mt * 32 + rg * 16;

    // A-frag source: lane holds A[m = mi][k = nh*2048 + q*8 + j], contiguous fp32.
    const float* aptr = assoc + ((size_t)b * Mm + (size_t)(m0 + mi)) * Nn
                      + nh * (Nn / 2) + q * 8;
    // B-frag source: lane holds B[k][n = d], contiguous in Ft[d][k]; d = mi + 16*db.
    const unsigned short* fptr = ft + (size_t)b * Dd * Nn + (size_t)mi * Nn
                               + nh * (Nn / 2) + q * 8;

    floatx4 acc0 = {0.f, 0.f, 0.f, 0.f};
    floatx4 acc1 = acc0, acc2 = acc0, acc3 = acc0;
    float s0 = 0.f, s1 = 0.f;                // row-sum partials (break the dep chain)

    // 64 iterations of K=32 — identical body to the proven v1 loop.
    #pragma unroll 4
    for (int k0 = 0; k0 < Nn / 2; k0 += 32) {
        float4 alo = *(const float4*)(aptr + k0);
        float4 ahi = *(const float4*)(aptr + k0 + 4);
        float av[8] = {alo.x, alo.y, alo.z, alo.w, ahi.x, ahi.y, ahi.z, ahi.w};

        short8_t afrag;
        #pragma unroll
        for (int j = 0; j < 8; ++j) {
            unsigned short h = f32_to_bf16_rne(av[j] + EPS_VAL);
            afrag[j] = (short)h;
            float hv = __uint_as_float(((unsigned)h) << 16);
            if (j & 1) s1 += hv; else s0 += hv;
        }

        short8_t bf0 = *(const short8_t*)(fptr + k0);
        short8_t bf1 = *(const short8_t*)(fptr + k0 + 16 * Nn);
        short8_t bf2 = *(const short8_t*)(fptr + k0 + 32 * Nn);
        short8_t bf3 = *(const short8_t*)(fptr + k0 + 48 * Nn);

        acc0 = __builtin_amdgcn_mfma_f32_16x16x32_bf16(afrag, bf0, acc0, 0, 0, 0);
        acc1 = __builtin_amdgcn_mfma_f32_16x16x32_bf16(afrag, bf1, acc1, 0, 0, 0);
        acc2 = __builtin_amdgcn_mfma_f32_16x16x32_bf16(afrag, bf2, acc2, 0, 0, 0);
        acc3 = __builtin_amdgcn_mfma_f32_16x16x32_bf16(afrag, bf3, acc3, 0, 0, 0);
    }

    // Fold the quad partials within this wave: XOR over bits 4,5 sums all 4
    // k-slabs -> every lane holds this wave's partial S for row (l & 15).
    float s = s0 + s1;
    s += __shfl_xor(s, 16);
    s += __shfl_xor(s, 32);

    // Cross-wave pairwise reduction: nh==1 waves publish, nh==0 waves finish.
    // Stride 17 floats: conflict-free across 32 banks.
    __shared__ float red[2][64][17];
    if (nh == 1) {
        float* p = red[rg][l];
        #pragma unroll
        for (int i = 0; i < 4; ++i) {
            p[i]      = acc0[i];
            p[4 + i]  = acc1[i];
            p[8 + i]  = acc2[i];
            p[12 + i] = acc3[i];
        }
        p[16] = s;
    }
    __syncthreads();

    if (nh == 0) {
        const float* p = red[rg][l];
        #pragma unroll
        for (int i = 0; i < 4; ++i) {
            acc0[i] += p[i];
            acc1[i] += p[4 + i];
            acc2[i] += p[8 + i];
            acc3[i] += p[12 + i];
        }
        s += p[16];

        // C/D layout: col = l&15 (d), row = q*4 + reg (m). Need S for rows q*4+r.
        #pragma unroll
        for (int r = 0; r < 4; ++r) {
            float Sr  = __shfl(s, q * 4 + r);    // lane (q*4+r) holds S for row mi==q*4+r
            float inv = 1.0f / Sr;
            size_t base = ((size_t)b * Mm + (size_t)(m0 + q * 4 + r)) * Dd + mi;
            out[base +  0] = acc0[r] * inv;
            out[base + 16] = acc1[r] * inv;
            out[base + 32] = acc2[r] * inv;
            out[base + 48] = acc3[r] * inv;
        }
    }
}

extern "C" void kernel_launch(void* const* d_in, const int* in_sizes, int n_in,
                              void* d_out, int out_size, void* d_ws, size_t ws_size,
                              hipStream_t stream) {
    const float* feat  = (const float*)d_in[0];   // [B,N,D] fp32
    const float* assoc = (const float*)d_in[1];   // [B,M,N] fp32
    float* out = (float*)d_out;                   // [B,M,D] fp32
    unsigned short* ft = (unsigned short*)d_ws;   // [B,D,N] bf16 scratch (2 MB)

    hipLaunchKernelGGL(transpose_feat_kernel, dim3(Bn * (Nn / 64)), dim3(256), 0, stream,
                       feat, ft);
    hipLaunchKernelGGL(agg_kernel, dim3(Bn * (Mm / 32)), dim3(256), 0, stream,
                       assoc, ft, out);
}